// Round 1
// baseline (949.561 us; speedup 1.0000x reference)
//
#include <hip/hip_runtime.h>
#include <hip/hip_bf16.h>

// Problem shapes (fixed by setup_inputs):
//   b=2, L=1024, d_model=1024, d_inner=2048, d_state=16, D_CONV=4
//   tokens N = b*L = 2048
#define NTOK   2048
#define DMODEL 1024
#define DINNER 2048
#define DSTATE 16
#define SEQLEN 1024
#define NPROJ  33   // 2*d_state + 1

// ---------------------------------------------------------------------------
// GEMM: C[n,m] = sum_k A[n,k] * B[m,k] (+ bias[m])   (A row-major NxK, B row-major MxK)
// 64x64 tile, BK=16, 256 threads, 4x4 micro-tile per thread. All dims divide evenly.
// ---------------------------------------------------------------------------
__global__ __launch_bounds__(256) void gemm_bt_kernel(
    const float* __restrict__ A, const float* __restrict__ B,
    const float* __restrict__ bias, float* __restrict__ C,
    int N, int M, int K) {
  constexpr int BM = 64, BN = 64, BK = 16;
  __shared__ float As[BK][BM + 4];
  __shared__ float Bs[BK][BN + 4];

  const int tid = threadIdx.x;
  const int n0 = blockIdx.x * BM;
  const int m0 = blockIdx.y * BN;

  // load mapping: 256 threads cover 64 rows x 4 float4 (16 k's)
  const int lr = tid >> 2;          // 0..63 tile row
  const int lk = (tid & 3) * 4;     // 0,4,8,12
  // compute mapping: 16x16 thread grid, 4x4 each
  const int tm = (tid >> 4) * 4;
  const int tn = (tid & 15) * 4;

  float acc[4][4] = {};

  const float* Aptr = A + (size_t)(n0 + lr) * K + lk;
  const float* Bptr = B + (size_t)(m0 + lr) * K + lk;

  for (int k0 = 0; k0 < K; k0 += BK) {
    const float4 a4 = *(const float4*)(Aptr + k0);
    const float4 b4 = *(const float4*)(Bptr + k0);
    __syncthreads();  // previous iteration's reads complete before overwrite
    As[lk + 0][lr] = a4.x; As[lk + 1][lr] = a4.y;
    As[lk + 2][lr] = a4.z; As[lk + 3][lr] = a4.w;
    Bs[lk + 0][lr] = b4.x; Bs[lk + 1][lr] = b4.y;
    Bs[lk + 2][lr] = b4.z; Bs[lk + 3][lr] = b4.w;
    __syncthreads();
#pragma unroll
    for (int k = 0; k < BK; ++k) {
      const float4 av = *(const float4*)&As[k][tm];
      const float4 bv = *(const float4*)&Bs[k][tn];
      const float a[4] = {av.x, av.y, av.z, av.w};
      const float bb[4] = {bv.x, bv.y, bv.z, bv.w};
#pragma unroll
      for (int i = 0; i < 4; ++i)
#pragma unroll
        for (int j = 0; j < 4; ++j)
          acc[i][j] = fmaf(a[i], bb[j], acc[i][j]);
    }
  }

#pragma unroll
  for (int i = 0; i < 4; ++i) {
    float* crow = C + (size_t)(n0 + tm + i) * M + m0 + tn;
#pragma unroll
    for (int j = 0; j < 4; ++j) {
      float v = acc[i][j];
      if (bias) v += bias[m0 + tn + j];
      crow[j] = v;
    }
  }
}

// ---------------------------------------------------------------------------
// Depthwise causal conv (width 4) + SiLU gating.
//   xz: (NTOK, 2*DINNER), first DINNER = xh, last DINNER = z
//   xg[n,i] = (conv_b[i] + sum_k w[i,k]*xh[n+k-3, i]) * silu(z[n,i])
// (conv is per-sequence causal; n = b*SEQLEN + l, taps only within same b)
// ---------------------------------------------------------------------------
__global__ __launch_bounds__(256) void conv_gate_kernel(
    const float* __restrict__ xz, const float* __restrict__ cw,
    const float* __restrict__ cb, float* __restrict__ xg) {
  const int idx = blockIdx.x * 256 + threadIdx.x;  // over NTOK*DINNER
  const int i = idx & (DINNER - 1);
  const int n = idx >> 11;  // DINNER = 2048 = 2^11
  const int l = n & (SEQLEN - 1);

  const float4 w4 = ((const float4*)cw)[i];  // conv_w[i,0,0..3]
  const float* base = xz + (size_t)n * (2 * DINNER) + i;

  float acc = cb[i] + w4.w * base[0];
  if (l >= 1) acc = fmaf(w4.z, base[-(2 * DINNER)], acc);
  if (l >= 2) acc = fmaf(w4.y, base[-2 * (2 * DINNER)], acc);
  if (l >= 3) acc = fmaf(w4.x, base[-3 * (2 * DINNER)], acc);

  const float z = base[DINNER];
  const float sig = 1.f / (1.f + __expf(-z));
  xg[idx] = acc * (z * sig);
}

// ---------------------------------------------------------------------------
// x-projection: proj[n,r] = sum_i xg[n,i] * xproj_w[r,i]   (r < 33, K = 2048)
// one wave per token; lane-strided float4 loads; shuffle reduce per r.
// ---------------------------------------------------------------------------
__global__ __launch_bounds__(64) void xproj_kernel(
    const float* __restrict__ xg, const float* __restrict__ w,
    float* __restrict__ proj) {
  const int n = blockIdx.x;
  const int lane = threadIdx.x;  // 0..63
  const float* row = xg + (size_t)n * DINNER;

  float4 xv[8];
#pragma unroll
  for (int j = 0; j < 8; ++j)
    xv[j] = *(const float4*)(row + j * 256 + lane * 4);

  for (int r = 0; r < NPROJ; ++r) {
    const float* wr = w + (size_t)r * DINNER;
    float p = 0.f;
#pragma unroll
    for (int j = 0; j < 8; ++j) {
      const float4 wv = *(const float4*)(wr + j * 256 + lane * 4);
      p = fmaf(xv[j].x, wv.x, p);
      p = fmaf(xv[j].y, wv.y, p);
      p = fmaf(xv[j].z, wv.z, p);
      p = fmaf(xv[j].w, wv.w, p);
    }
#pragma unroll
    for (int off = 32; off >= 1; off >>= 1) p += __shfl_down(p, off, 64);
    if (lane == 0) proj[(size_t)n * NPROJ + r] = p;
  }
}

// ---------------------------------------------------------------------------
// Selective scan. One thread per (b, channel i). Sequential over L.
//   u      = proj[n,0]*dt_w[i] + dt_b[i]
//   delta  = exp(softplus(u)) = 1 + exp(u)        (exact identity)
//   h[s]   = exp(A[i,s]*delta)*h[s] + delta*B[n,s]*x
//   y[n,i] = sum_s h[s]*C[n,s] + D[i]*x
// ---------------------------------------------------------------------------
__global__ __launch_bounds__(64) void scan_kernel(
    const float* __restrict__ xg, const float* __restrict__ proj,
    const float* __restrict__ dt_w, const float* __restrict__ dt_b,
    const float* __restrict__ A_log, const float* __restrict__ Dp,
    float* __restrict__ y) {
  const int b = blockIdx.y;
  const int i = blockIdx.x * 64 + threadIdx.x;

  const float dtw = dt_w[i];
  const float dtb = dt_b[i];
  const float Dv = Dp[i];

  float Av[DSTATE];
#pragma unroll
  for (int s = 0; s < DSTATE; ++s) Av[s] = -__expf(A_log[i * DSTATE + s]);

  float h[DSTATE];
#pragma unroll
  for (int s = 0; s < DSTATE; ++s) h[s] = 0.f;

  for (int t = 0; t < SEQLEN; ++t) {
    const int n = b * SEQLEN + t;
    const float* pr = proj + (size_t)n * NPROJ;  // wave-uniform address
    const float u = fmaf(pr[0], dtw, dtb);
    const float delta = 1.f + __expf(u);
    const float x = xg[(size_t)n * DINNER + i];
    const float dx = delta * x;
    float yt = 0.f;
#pragma unroll
    for (int s = 0; s < DSTATE; ++s) {
      const float Ab = __expf(Av[s] * delta);
      h[s] = fmaf(Ab, h[s], pr[1 + s] * dx);
      yt = fmaf(h[s], pr[1 + DSTATE + s], yt);
    }
    y[(size_t)n * DINNER + i] = fmaf(Dv, x, yt);
  }
}

// ---------------------------------------------------------------------------
extern "C" void kernel_launch(void* const* d_in, const int* in_sizes, int n_in,
                              void* d_out, int out_size, void* d_ws, size_t ws_size,
                              hipStream_t stream) {
  const float* x       = (const float*)d_in[0];   // (2,1024,1024)
  const float* in_w    = (const float*)d_in[1];   // (4096,1024)
  const float* in_b    = (const float*)d_in[2];   // (4096,)
  const float* conv_w  = (const float*)d_in[3];   // (2048,1,4)
  const float* conv_b  = (const float*)d_in[4];   // (2048,)
  const float* xproj_w = (const float*)d_in[5];   // (33,2048)
  const float* dt_w    = (const float*)d_in[6];   // (2048,1)
  const float* dt_b    = (const float*)d_in[7];   // (2048,)
  const float* A_log   = (const float*)d_in[8];   // (2048,16)
  const float* Dp      = (const float*)d_in[9];   // (2048,)
  const float* out_w   = (const float*)d_in[10];  // (1024,2048)
  float* out = (float*)d_out;                     // (2,1024,1024)

  // Workspace layout (floats):
  //   region0 [0 .. 8388608): xz (2048 x 4096) -- dead after conv_gate;
  //           reused: y (2048 x 2048) at offset 0, proj (2048 x 33) at +4194304
  //   region1 [8388608 .. 12582912): xg (2048 x 2048)
  float* ws = (float*)d_ws;
  float* xz   = ws;                 // 2048*4096
  float* yb   = ws;                 // 2048*2048 (aliases dead xz)
  float* proj = ws + 4194304;       // 2048*33   (aliases dead xz upper half)
  float* xg   = ws + 8388608;       // 2048*2048

  // 1. in-projection: xz = x @ in_w.T + in_b       (2048 x 4096, K=1024)
  gemm_bt_kernel<<<dim3(NTOK / 64, (2 * DINNER) / 64), 256, 0, stream>>>(
      x, in_w, in_b, xz, NTOK, 2 * DINNER, DMODEL);

  // 2. depthwise conv + SiLU gate -> xg            (2048 x 2048)
  conv_gate_kernel<<<(NTOK * DINNER) / 256, 256, 0, stream>>>(
      xz, conv_w, conv_b, xg);

  // 3. x-projection -> proj                        (2048 x 33)
  xproj_kernel<<<NTOK, 64, 0, stream>>>(xg, xproj_w, proj);

  // 4. selective scan -> yb                        (2048 x 2048)
  scan_kernel<<<dim3(DINNER / 64, 2), 64, 0, stream>>>(
      xg, proj, dt_w, dt_b, A_log, Dp, yb);

  // 5. out-projection: out = y @ out_w.T           (2048 x 1024, K=2048)
  gemm_bt_kernel<<<dim3(NTOK / 64, DMODEL / 64), 256, 0, stream>>>(
      yb, out_w, nullptr, out, NTOK, DMODEL, DINNER);
}

// Round 2
// 563.053 us; speedup vs baseline: 1.6865x; 1.6865x over previous
//
#include <hip/hip_runtime.h>
#include <hip/hip_bf16.h>

// Problem shapes (fixed by setup_inputs):
//   b=2, L=1024, d_model=1024, d_inner=2048, d_state=16, D_CONV=4
#define NTOK   2048
#define DMODEL 1024
#define DINNER 2048
#define DSTATE 16
#define SEQLEN 1024
#define NPROJ  33   // 2*d_state + 1
#define CCH    32   // scan chunks per sequence
#define CT     32   // steps per chunk (CCH*CT == SEQLEN)

// ---------------------------------------------------------------------------
// GEMM: C[n,m] = sum_k A[n,k] * B[m,k] (+ bias[m])
// ---------------------------------------------------------------------------
__global__ __launch_bounds__(256) void gemm_bt_kernel(
    const float* __restrict__ A, const float* __restrict__ B,
    const float* __restrict__ bias, float* __restrict__ C,
    int N, int M, int K) {
  constexpr int BM = 64, BN = 64, BK = 16;
  __shared__ float As[BK][BM + 4];
  __shared__ float Bs[BK][BN + 4];

  const int tid = threadIdx.x;
  const int n0 = blockIdx.x * BM;
  const int m0 = blockIdx.y * BN;

  const int lr = tid >> 2;
  const int lk = (tid & 3) * 4;
  const int tm = (tid >> 4) * 4;
  const int tn = (tid & 15) * 4;

  float acc[4][4] = {};

  const float* Aptr = A + (size_t)(n0 + lr) * K + lk;
  const float* Bptr = B + (size_t)(m0 + lr) * K + lk;

  for (int k0 = 0; k0 < K; k0 += BK) {
    const float4 a4 = *(const float4*)(Aptr + k0);
    const float4 b4 = *(const float4*)(Bptr + k0);
    __syncthreads();
    As[lk + 0][lr] = a4.x; As[lk + 1][lr] = a4.y;
    As[lk + 2][lr] = a4.z; As[lk + 3][lr] = a4.w;
    Bs[lk + 0][lr] = b4.x; Bs[lk + 1][lr] = b4.y;
    Bs[lk + 2][lr] = b4.z; Bs[lk + 3][lr] = b4.w;
    __syncthreads();
#pragma unroll
    for (int k = 0; k < BK; ++k) {
      const float4 av = *(const float4*)&As[k][tm];
      const float4 bv = *(const float4*)&Bs[k][tn];
      const float a[4] = {av.x, av.y, av.z, av.w};
      const float bb[4] = {bv.x, bv.y, bv.z, bv.w};
#pragma unroll
      for (int i = 0; i < 4; ++i)
#pragma unroll
        for (int j = 0; j < 4; ++j)
          acc[i][j] = fmaf(a[i], bb[j], acc[i][j]);
    }
  }

#pragma unroll
  for (int i = 0; i < 4; ++i) {
    float* crow = C + (size_t)(n0 + tm + i) * M + m0 + tn;
#pragma unroll
    for (int j = 0; j < 4; ++j) {
      float v = acc[i][j];
      if (bias) v += bias[m0 + tn + j];
      crow[j] = v;
    }
  }
}

// ---------------------------------------------------------------------------
// Depthwise causal conv (width 4) + SiLU gating.
// ---------------------------------------------------------------------------
__global__ __launch_bounds__(256) void conv_gate_kernel(
    const float* __restrict__ xz, const float* __restrict__ cw,
    const float* __restrict__ cb, float* __restrict__ xg) {
  const int idx = blockIdx.x * 256 + threadIdx.x;
  const int i = idx & (DINNER - 1);
  const int n = idx >> 11;
  const int l = n & (SEQLEN - 1);

  const float4 w4 = ((const float4*)cw)[i];
  const float* base = xz + (size_t)n * (2 * DINNER) + i;

  float acc = cb[i] + w4.w * base[0];
  if (l >= 1) acc = fmaf(w4.z, base[-(2 * DINNER)], acc);
  if (l >= 2) acc = fmaf(w4.y, base[-2 * (2 * DINNER)], acc);
  if (l >= 3) acc = fmaf(w4.x, base[-3 * (2 * DINNER)], acc);

  const float z = base[DINNER];
  const float sig = 1.f / (1.f + __expf(-z));
  xg[idx] = acc * (z * sig);
}

// ---------------------------------------------------------------------------
// x-projection: proj[n,r] = sum_i xg[n,i] * xproj_w[r,i]
// ---------------------------------------------------------------------------
__global__ __launch_bounds__(64) void xproj_kernel(
    const float* __restrict__ xg, const float* __restrict__ w,
    float* __restrict__ proj) {
  const int n = blockIdx.x;
  const int lane = threadIdx.x;
  const float* row = xg + (size_t)n * DINNER;

  float4 xv[8];
#pragma unroll
  for (int j = 0; j < 8; ++j)
    xv[j] = *(const float4*)(row + j * 256 + lane * 4);

  for (int r = 0; r < NPROJ; ++r) {
    const float* wr = w + (size_t)r * DINNER;
    float p = 0.f;
#pragma unroll
    for (int j = 0; j < 8; ++j) {
      const float4 wv = *(const float4*)(wr + j * 256 + lane * 4);
      p = fmaf(xv[j].x, wv.x, p);
      p = fmaf(xv[j].y, wv.y, p);
      p = fmaf(xv[j].z, wv.z, p);
      p = fmaf(xv[j].w, wv.w, p);
    }
#pragma unroll
    for (int off = 32; off >= 1; off >>= 1) p += __shfl_down(p, off, 64);
    if (lane == 0) proj[(size_t)n * NPROJ + r] = p;
  }
}

// ---------------------------------------------------------------------------
// Chunked selective scan.
//   delta = 1 + exp(u)  (== exp(softplus(u)), exact)
//   h[s]  <- exp(Av[s]*delta)*h[s] + delta*B*x
// Phase 1: per (b,i,chunk) scan from h=0 -> Hend[16], Ssum (sum of deltas;
//          chunk decay = exp(Av*Ssum) since prod(exp) = exp(sum)).
// Phase 2: per (b,i,s) compose across the 32 chunks -> h0 per chunk (inplace).
// Phase 3: per (b,i,chunk) re-scan seeded with h0, emit y.
// ---------------------------------------------------------------------------
__global__ __launch_bounds__(256) void scan_phase1(
    const float* __restrict__ xg, const float* __restrict__ proj,
    const float* __restrict__ dt_w, const float* __restrict__ dt_b,
    const float* __restrict__ A_log,
    float* __restrict__ Sbuf, float* __restrict__ Hbuf) {
  __shared__ float pl[CT][36];
  const int tid = threadIdx.x;
  const int i = blockIdx.x * 256 + tid;
  const int k = blockIdx.y;
  const int b = blockIdx.z;
  const int n0 = b * SEQLEN + k * CT;

  for (int e = tid; e < CT * NPROJ; e += 256) {
    const int t = e / NPROJ;
    const int c = e - t * NPROJ;
    pl[t][c] = proj[(size_t)(n0 + t) * NPROJ + c];
  }
  __syncthreads();

  const float dtw = dt_w[i], dtb = dt_b[i];
  float Av[DSTATE];
#pragma unroll
  for (int s = 0; s < DSTATE; ++s) Av[s] = -__expf(A_log[i * DSTATE + s]);

  float h[DSTATE] = {};
  float Ssum = 0.f;

  for (int t = 0; t < CT; ++t) {
    float fr[20];
#pragma unroll
    for (int j = 0; j < 5; ++j) {
      const float4 v = *(const float4*)&pl[t][j * 4];
      fr[4 * j + 0] = v.x; fr[4 * j + 1] = v.y;
      fr[4 * j + 2] = v.z; fr[4 * j + 3] = v.w;
    }
    const float delta = 1.f + __expf(fmaf(fr[0], dtw, dtb));
    Ssum += delta;
    const float x = xg[(size_t)(n0 + t) * DINNER + i];
    const float dx = delta * x;
#pragma unroll
    for (int s = 0; s < DSTATE; ++s)
      h[s] = fmaf(__expf(Av[s] * delta), h[s], fr[1 + s] * dx);
  }

  const size_t ck = (size_t)(b * CCH + k) * DINNER + i;
  Sbuf[ck] = Ssum;
  float4* Hq = (float4*)(Hbuf + ck * DSTATE);
#pragma unroll
  for (int q = 0; q < 4; ++q)
    Hq[q] = make_float4(h[4 * q], h[4 * q + 1], h[4 * q + 2], h[4 * q + 3]);
}

__global__ __launch_bounds__(256) void scan_phase2(
    const float* __restrict__ A_log, const float* __restrict__ Sbuf,
    float* __restrict__ Hbuf) {
  const int gid = blockIdx.x * 256 + threadIdx.x;  // over 2*DINNER*DSTATE
  const int s = gid & (DSTATE - 1);
  const int i = (gid >> 4) & (DINNER - 1);
  const int b = gid >> 15;
  const float Av = -__expf(A_log[i * DSTATE + s]);
  float H = 0.f;
  for (int k = 0; k < CCH; ++k) {
    const size_t ck = (size_t)(b * CCH + k) * DINNER + i;
    const float hk = Hbuf[ck * DSTATE + s];
    const float a = __expf(Av * Sbuf[ck]);
    Hbuf[ck * DSTATE + s] = H;   // h0 for chunk k
    H = fmaf(a, H, hk);
  }
}

__global__ __launch_bounds__(256) void scan_phase3(
    const float* __restrict__ xg, const float* __restrict__ proj,
    const float* __restrict__ dt_w, const float* __restrict__ dt_b,
    const float* __restrict__ A_log, const float* __restrict__ Dp,
    const float* __restrict__ Hbuf, float* __restrict__ y) {
  __shared__ float pl[CT][36];
  const int tid = threadIdx.x;
  const int i = blockIdx.x * 256 + tid;
  const int k = blockIdx.y;
  const int b = blockIdx.z;
  const int n0 = b * SEQLEN + k * CT;

  for (int e = tid; e < CT * NPROJ; e += 256) {
    const int t = e / NPROJ;
    const int c = e - t * NPROJ;
    pl[t][c] = proj[(size_t)(n0 + t) * NPROJ + c];
  }
  __syncthreads();

  const float dtw = dt_w[i], dtb = dt_b[i];
  const float Dv = Dp[i];
  float Av[DSTATE];
#pragma unroll
  for (int s = 0; s < DSTATE; ++s) Av[s] = -__expf(A_log[i * DSTATE + s]);

  const size_t ck = (size_t)(b * CCH + k) * DINNER + i;
  float h[DSTATE];
  const float4* Hq = (const float4*)(Hbuf + ck * DSTATE);
#pragma unroll
  for (int q = 0; q < 4; ++q) {
    const float4 v = Hq[q];
    h[4 * q + 0] = v.x; h[4 * q + 1] = v.y;
    h[4 * q + 2] = v.z; h[4 * q + 3] = v.w;
  }

  for (int t = 0; t < CT; ++t) {
    float fr[33];
#pragma unroll
    for (int j = 0; j < 8; ++j) {
      const float4 v = *(const float4*)&pl[t][j * 4];
      fr[4 * j + 0] = v.x; fr[4 * j + 1] = v.y;
      fr[4 * j + 2] = v.z; fr[4 * j + 3] = v.w;
    }
    fr[32] = pl[t][32];
    const float delta = 1.f + __expf(fmaf(fr[0], dtw, dtb));
    const float x = xg[(size_t)(n0 + t) * DINNER + i];
    const float dx = delta * x;
    float yt = 0.f;
#pragma unroll
    for (int s = 0; s < DSTATE; ++s) {
      h[s] = fmaf(__expf(Av[s] * delta), h[s], fr[1 + s] * dx);
      yt = fmaf(h[s], fr[17 + s], yt);
    }
    y[(size_t)(n0 + t) * DINNER + i] = fmaf(Dv, x, yt);
  }
}

// ---------------------------------------------------------------------------
extern "C" void kernel_launch(void* const* d_in, const int* in_sizes, int n_in,
                              void* d_out, int out_size, void* d_ws, size_t ws_size,
                              hipStream_t stream) {
  const float* x       = (const float*)d_in[0];
  const float* in_w    = (const float*)d_in[1];
  const float* in_b    = (const float*)d_in[2];
  const float* conv_w  = (const float*)d_in[3];
  const float* conv_b  = (const float*)d_in[4];
  const float* xproj_w = (const float*)d_in[5];
  const float* dt_w    = (const float*)d_in[6];
  const float* dt_b    = (const float*)d_in[7];
  const float* A_log   = (const float*)d_in[8];
  const float* Dp      = (const float*)d_in[9];
  const float* out_w   = (const float*)d_in[10];
  float* out = (float*)d_out;

  // Workspace (floats). xz occupies [0, 8M) and is DEAD after conv_gate;
  // everything below at offsets < 8M aliases that dead region.
  //   xz   @ 0         : 2048*4096 = 8M           (gemm1 -> conv)
  //   xg   @ 8388608   : 2048*2048 = 4M           (conv -> phase3)
  //   proj @ 0         : 2048*33   = 67584        (xproj -> phase1/3)
  //   Sbuf @ 131072    : 2*32*2048 = 131072       (phase1 -> phase2)
  //   Hbuf @ 262144    : 2*32*2048*16 = 2097152   (phase1 -> phase2 -> phase3)
  //   yb   @ 4194304   : 2048*2048 = 4M           (phase3 -> gemm2)
  float* ws = (float*)d_ws;
  float* xz   = ws;
  float* proj = ws;
  float* Sbuf = ws + 131072;
  float* Hbuf = ws + 262144;
  float* yb   = ws + 4194304;
  float* xg   = ws + 8388608;

  // 1. in-projection: xz = x @ in_w.T + in_b
  gemm_bt_kernel<<<dim3(NTOK / 64, (2 * DINNER) / 64), 256, 0, stream>>>(
      x, in_w, in_b, xz, NTOK, 2 * DINNER, DMODEL);

  // 2. depthwise conv + SiLU gate -> xg
  conv_gate_kernel<<<(NTOK * DINNER) / 256, 256, 0, stream>>>(
      xz, conv_w, conv_b, xg);

  // 3. x-projection -> proj
  xproj_kernel<<<NTOK, 64, 0, stream>>>(xg, xproj_w, proj);

  // 4. chunked selective scan -> yb
  scan_phase1<<<dim3(DINNER / 256, CCH, 2), 256, 0, stream>>>(
      xg, proj, dt_w, dt_b, A_log, Sbuf, Hbuf);
  scan_phase2<<<(2 * DINNER * DSTATE) / 256, 256, 0, stream>>>(
      A_log, Sbuf, Hbuf);
  scan_phase3<<<dim3(DINNER / 256, CCH, 2), 256, 0, stream>>>(
      xg, proj, dt_w, dt_b, A_log, Dp, Hbuf, yb);

  // 5. out-projection: out = y @ out_w.T
  gemm_bt_kernel<<<dim3(NTOK / 64, DMODEL / 64), 256, 0, stream>>>(
      yb, out_w, nullptr, out, NTOK, DMODEL, DINNER);
}

// Round 4
// 264.078 us; speedup vs baseline: 3.5958x; 2.1321x over previous
//
#include <hip/hip_runtime.h>
#include <hip/hip_bf16.h>

// Problem shapes (fixed by setup_inputs):
//   b=2, L=1024, d_model=1024, d_inner=2048, d_state=16, D_CONV=4
#define NTOK   2048
#define DMODEL 1024
#define DINNER 2048
#define DSTATE 16
#define SEQLEN 1024
#define NPROJ  33   // 2*d_state + 1
#define CCH    32   // scan chunks per sequence
#define CT     32   // steps per chunk

typedef __attribute__((ext_vector_type(8))) short bf16x8;
typedef __attribute__((ext_vector_type(4))) float f32x4;
typedef __attribute__((ext_vector_type(8))) unsigned short us8;

__device__ __forceinline__ unsigned short f2bf(float f) {
  unsigned u = __float_as_uint(f);
  return (unsigned short)((u + 0x7FFFu + ((u >> 16) & 1u)) >> 16);  // RNE
}

__device__ __forceinline__ void gload_lds16(const void* g, void* l) {
  __builtin_amdgcn_global_load_lds(
      (const __attribute__((address_space(1))) unsigned int*)g,
      (__attribute__((address_space(3))) unsigned int*)l, 16, 0, 0);
}

// ---------------------------------------------------------------------------
// fp32 -> bf16 cast, 8 elems/thread (n must be a multiple of 8)
// ---------------------------------------------------------------------------
__global__ __launch_bounds__(256) void cast_bf16_kernel(
    const float* __restrict__ src, unsigned short* __restrict__ dst, int n) {
  const int idx = (blockIdx.x * 256 + threadIdx.x) * 8;
  if (idx >= n) return;
  const float4 a = *(const float4*)(src + idx);
  const float4 b = *(const float4*)(src + idx + 4);
  us8 o;
  o[0] = f2bf(a.x); o[1] = f2bf(a.y); o[2] = f2bf(a.z); o[3] = f2bf(a.w);
  o[4] = f2bf(b.x); o[5] = f2bf(b.y); o[6] = f2bf(b.z); o[7] = f2bf(b.w);
  *(us8*)(dst + idx) = o;
}

// ---------------------------------------------------------------------------
// bf16 MFMA GEMM (m97 structure): C[n,m] = sum_k A[n,k]*B[m,k] (+ bias[m])
// A: NTOKxK bf16 row-major, B: MxK bf16 row-major. Block tile 128 x BN, BK=32.
// 256 threads = 4 waves in 2x2; wave tile 64 x BN/2 of 16x16x32 MFMAs.
// LDS staging via global_load_lds width-16 (wave-uniform base + lane*16).
// ---------------------------------------------------------------------------
template <int BN>
__global__ __launch_bounds__(256) void gemm_bt_mfma(
    const unsigned short* __restrict__ A, const unsigned short* __restrict__ B,
    const float* __restrict__ bias, float* __restrict__ C, int M, int K) {
  constexpr int TN = BN / 32;          // mfma tiles per wave in n
  __shared__ unsigned short As[128 * 32];
  __shared__ unsigned short Bs[BN * 32];

  const int tid = threadIdx.x;
  const int wid = tid >> 6;            // wave id 0..3 (uniform per wave)
  const int lane = tid & 63;
  const int n0 = blockIdx.x * 128;     // token tile
  const int m0 = blockIdx.y * BN;      // feature tile

  const int wave_m = wid & 1;          // 0..1
  const int wave_n = wid >> 1;         // 0..1
  const int lm = lane & 15;            // fragment row/col within 16
  const int lq = lane >> 4;            // k-quad 0..3

  f32x4 acc[4][TN] = {};

  for (int k0 = 0; k0 < K; k0 += 32) {
    __syncthreads();  // prior iter's ds_reads complete before overwrite
    // stage A: 512 x 16B chunks; chunk c -> row c>>2, k-offset (c&3)*8
#pragma unroll
    for (int j = 0; j < 2; ++j) {
      const int cb = j * 256 + wid * 64;         // wave-uniform chunk base
      const int c = cb + lane;
      gload_lds16(A + (size_t)(n0 + (c >> 2)) * K + k0 + (c & 3) * 8,
                  &As[cb * 8]);
    }
    // stage B: BN*4 chunks
#pragma unroll
    for (int j = 0; j < BN / 64; ++j) {
      const int cb = j * 256 + wid * 64;
      const int c = cb + lane;
      gload_lds16(B + (size_t)(m0 + (c >> 2)) * K + k0 + (c & 3) * 8,
                  &Bs[cb * 8]);
    }
    __syncthreads();  // compiler emits vmcnt(0) drain before barrier

    bf16x8 af[4], bfr[TN];
#pragma unroll
    for (int tm = 0; tm < 4; ++tm)
      af[tm] = *(const bf16x8*)&As[(wave_m * 64 + tm * 16 + lm) * 32 + lq * 8];
#pragma unroll
    for (int tn = 0; tn < TN; ++tn)
      bfr[tn] = *(const bf16x8*)&Bs[(wave_n * (BN / 2) + tn * 16 + lm) * 32 + lq * 8];
#pragma unroll
    for (int tm = 0; tm < 4; ++tm)
#pragma unroll
      for (int tn = 0; tn < TN; ++tn)
        acc[tm][tn] = __builtin_amdgcn_mfma_f32_16x16x32_bf16(
            af[tm], bfr[tn], acc[tm][tn], 0, 0, 0);
  }

  // C/D layout: reg r of lane holds D[row=(lane>>4)*4+r][col=lane&15]
#pragma unroll
  for (int tm = 0; tm < 4; ++tm) {
    const int row = n0 + wave_m * 64 + tm * 16 + lq * 4;
#pragma unroll
    for (int tn = 0; tn < TN; ++tn) {
      const int col = m0 + wave_n * (BN / 2) + tn * 16 + lm;
      const float bv = bias ? bias[col] : 0.f;
#pragma unroll
      for (int r = 0; r < 4; ++r)
        C[(size_t)(row + r) * M + col] = acc[tm][tn][r] + bv;
    }
  }
}

// ---------------------------------------------------------------------------
// Depthwise causal conv (width 4) + SiLU gating.
// ---------------------------------------------------------------------------
__global__ __launch_bounds__(256) void conv_gate_kernel(
    const float* __restrict__ xz, const float* __restrict__ cw,
    const float* __restrict__ cb, float* __restrict__ xg) {
  const int idx = blockIdx.x * 256 + threadIdx.x;
  const int i = idx & (DINNER - 1);
  const int n = idx >> 11;
  const int l = n & (SEQLEN - 1);

  const float4 w4 = ((const float4*)cw)[i];
  const float* base = xz + (size_t)n * (2 * DINNER) + i;

  float acc = cb[i] + w4.w * base[0];
  if (l >= 1) acc = fmaf(w4.z, base[-(2 * DINNER)], acc);
  if (l >= 2) acc = fmaf(w4.y, base[-2 * (2 * DINNER)], acc);
  if (l >= 3) acc = fmaf(w4.x, base[-3 * (2 * DINNER)], acc);

  const float z = base[DINNER];
  const float sig = 1.f / (1.f + __expf(-z));
  xg[idx] = acc * (z * sig);
}

// ---------------------------------------------------------------------------
// x-projection: proj[n,r] = sum_i xg[n,i] * xproj_w[r,i]
// ---------------------------------------------------------------------------
__global__ __launch_bounds__(64) void xproj_kernel(
    const float* __restrict__ xg, const float* __restrict__ w,
    float* __restrict__ proj) {
  const int n = blockIdx.x;
  const int lane = threadIdx.x;
  const float* row = xg + (size_t)n * DINNER;

  float4 xv[8];
#pragma unroll
  for (int j = 0; j < 8; ++j)
    xv[j] = *(const float4*)(row + j * 256 + lane * 4);

  for (int r = 0; r < NPROJ; ++r) {
    const float* wr = w + (size_t)r * DINNER;
    float p = 0.f;
#pragma unroll
    for (int j = 0; j < 8; ++j) {
      const float4 wv = *(const float4*)(wr + j * 256 + lane * 4);
      p = fmaf(xv[j].x, wv.x, p);
      p = fmaf(xv[j].y, wv.y, p);
      p = fmaf(xv[j].z, wv.z, p);
      p = fmaf(xv[j].w, wv.w, p);
    }
#pragma unroll
    for (int off = 32; off >= 1; off >>= 1) p += __shfl_down(p, off, 64);
    if (lane == 0) proj[(size_t)n * NPROJ + r] = p;
  }
}

// ---------------------------------------------------------------------------
// Chunked selective scan (delta = 1+exp(u) == exp(softplus(u)); chunk decay
// exp(Av*sum(delta)) since prod(exp) = exp(sum)).
// ---------------------------------------------------------------------------
__global__ __launch_bounds__(256) void scan_phase1(
    const float* __restrict__ xg, const float* __restrict__ proj,
    const float* __restrict__ dt_w, const float* __restrict__ dt_b,
    const float* __restrict__ A_log,
    float* __restrict__ Sbuf, float* __restrict__ Hbuf) {
  __shared__ float pl[CT][36];
  const int tid = threadIdx.x;
  const int i = blockIdx.x * 256 + tid;
  const int k = blockIdx.y;
  const int b = blockIdx.z;
  const int n0 = b * SEQLEN + k * CT;

  for (int e = tid; e < CT * NPROJ; e += 256) {
    const int t = e / NPROJ;
    const int c = e - t * NPROJ;
    pl[t][c] = proj[(size_t)(n0 + t) * NPROJ + c];
  }
  __syncthreads();

  const float dtw = dt_w[i], dtb = dt_b[i];
  float Av[DSTATE];
#pragma unroll
  for (int s = 0; s < DSTATE; ++s) Av[s] = -__expf(A_log[i * DSTATE + s]);

  float h[DSTATE] = {};
  float Ssum = 0.f;

  for (int t = 0; t < CT; ++t) {
    float fr[20];
#pragma unroll
    for (int j = 0; j < 5; ++j) {
      const float4 v = *(const float4*)&pl[t][j * 4];
      fr[4 * j + 0] = v.x; fr[4 * j + 1] = v.y;
      fr[4 * j + 2] = v.z; fr[4 * j + 3] = v.w;
    }
    const float delta = 1.f + __expf(fmaf(fr[0], dtw, dtb));
    Ssum += delta;
    const float x = xg[(size_t)(n0 + t) * DINNER + i];
    const float dx = delta * x;
#pragma unroll
    for (int s = 0; s < DSTATE; ++s)
      h[s] = fmaf(__expf(Av[s] * delta), h[s], fr[1 + s] * dx);
  }

  const size_t ck = (size_t)(b * CCH + k) * DINNER + i;
  Sbuf[ck] = Ssum;
  float4* Hq = (float4*)(Hbuf + ck * DSTATE);
#pragma unroll
  for (int q = 0; q < 4; ++q)
    Hq[q] = make_float4(h[4 * q], h[4 * q + 1], h[4 * q + 2], h[4 * q + 3]);
}

__global__ __launch_bounds__(256) void scan_phase2(
    const float* __restrict__ A_log, const float* __restrict__ Sbuf,
    float* __restrict__ Hbuf) {
  const int gid = blockIdx.x * 256 + threadIdx.x;
  const int s = gid & (DSTATE - 1);
  const int i = (gid >> 4) & (DINNER - 1);
  const int b = gid >> 15;
  const float Av = -__expf(A_log[i * DSTATE + s]);
  float H = 0.f;
  for (int k = 0; k < CCH; ++k) {
    const size_t ck = (size_t)(b * CCH + k) * DINNER + i;
    const float hk = Hbuf[ck * DSTATE + s];
    const float a = __expf(Av * Sbuf[ck]);
    Hbuf[ck * DSTATE + s] = H;
    H = fmaf(a, H, hk);
  }
}

__global__ __launch_bounds__(256) void scan_phase3(
    const float* __restrict__ xg, const float* __restrict__ proj,
    const float* __restrict__ dt_w, const float* __restrict__ dt_b,
    const float* __restrict__ A_log, const float* __restrict__ Dp,
    const float* __restrict__ Hbuf, unsigned short* __restrict__ y) {
  __shared__ float pl[CT][36];
  const int tid = threadIdx.x;
  const int i = blockIdx.x * 256 + tid;
  const int k = blockIdx.y;
  const int b = blockIdx.z;
  const int n0 = b * SEQLEN + k * CT;

  for (int e = tid; e < CT * NPROJ; e += 256) {
    const int t = e / NPROJ;
    const int c = e - t * NPROJ;
    pl[t][c] = proj[(size_t)(n0 + t) * NPROJ + c];
  }
  __syncthreads();

  const float dtw = dt_w[i], dtb = dt_b[i];
  const float Dv = Dp[i];
  float Av[DSTATE];
#pragma unroll
  for (int s = 0; s < DSTATE; ++s) Av[s] = -__expf(A_log[i * DSTATE + s]);

  const size_t ck = (size_t)(b * CCH + k) * DINNER + i;
  float h[DSTATE];
  const float4* Hq = (const float4*)(Hbuf + ck * DSTATE);
#pragma unroll
  for (int q = 0; q < 4; ++q) {
    const float4 v = Hq[q];
    h[4 * q + 0] = v.x; h[4 * q + 1] = v.y;
    h[4 * q + 2] = v.z; h[4 * q + 3] = v.w;
  }

  for (int t = 0; t < CT; ++t) {
    float fr[33];
#pragma unroll
    for (int j = 0; j < 8; ++j) {
      const float4 v = *(const float4*)&pl[t][j * 4];
      fr[4 * j + 0] = v.x; fr[4 * j + 1] = v.y;
      fr[4 * j + 2] = v.z; fr[4 * j + 3] = v.w;
    }
    fr[32] = pl[t][32];
    const float delta = 1.f + __expf(fmaf(fr[0], dtw, dtb));
    const float x = xg[(size_t)(n0 + t) * DINNER + i];
    const float dx = delta * x;
    float yt = 0.f;
#pragma unroll
    for (int s = 0; s < DSTATE; ++s) {
      h[s] = fmaf(__expf(Av[s] * delta), h[s], fr[1 + s] * dx);
      yt = fmaf(h[s], fr[17 + s], yt);
    }
    y[(size_t)(n0 + t) * DINNER + i] = f2bf(fmaf(Dv, x, yt));
  }
}

// ---------------------------------------------------------------------------
extern "C" void kernel_launch(void* const* d_in, const int* in_sizes, int n_in,
                              void* d_out, int out_size, void* d_ws, size_t ws_size,
                              hipStream_t stream) {
  const float* x       = (const float*)d_in[0];
  const float* in_w    = (const float*)d_in[1];
  const float* in_b    = (const float*)d_in[2];
  const float* conv_w  = (const float*)d_in[3];
  const float* conv_b  = (const float*)d_in[4];
  const float* xproj_w = (const float*)d_in[5];
  const float* dt_w    = (const float*)d_in[6];
  const float* dt_b    = (const float*)d_in[7];
  const float* A_log   = (const float*)d_in[8];
  const float* Dp      = (const float*)d_in[9];
  const float* out_w   = (const float*)d_in[10];
  float* out = (float*)d_out;

  // Workspace (float offsets; 12M floats = 48 MB total, liveness-overlapped):
  //  [0,8M)  xz fp32 (gemm1 -> conv; DEAD after conv). Overlaid after conv by:
  //     proj    @ 0       .. 67584      (xproj -> p1/p3)
  //     Sbuf    @ 131072  .. 262144     (p1 -> p2)
  //     Hbuf    @ 262144  .. 2359296    (p1 -> p2 -> p3)
  //     yb_bf   @ 2359296 .. 4456448    (p3 -> gemm2; 4M bf16 = 2M floats)
  //     outw_bf @ 4456448 .. 5505024    (cast AFTER conv; 2M bf16 = 1M floats)
  //  [8M,12M) xg fp32 (conv -> p1/p3). Before conv runs, overlaid by:
  //     x_bf    @ 8388608 (1M floats as 2M bf16; dead once gemm1 done)
  //     inw_bf  @ 9437184 (2M floats as 4M bf16; dead once gemm1 done)
  float* ws = (float*)d_ws;
  float* xz   = ws;
  float* proj = ws;
  float* Sbuf = ws + 131072;
  float* Hbuf = ws + 262144;
  unsigned short* yb_bf   = (unsigned short*)(ws + 2359296);
  unsigned short* outw_bf = (unsigned short*)(ws + 4456448);
  float* xg = ws + 8388608;
  unsigned short* x_bf   = (unsigned short*)(ws + 8388608);
  unsigned short* inw_bf = (unsigned short*)(ws + 9437184);

  // 0. casts for gemm1
  cast_bf16_kernel<<<(NTOK * DMODEL) / (256 * 8), 256, 0, stream>>>(
      x, x_bf, NTOK * DMODEL);
  cast_bf16_kernel<<<(2 * DINNER * DMODEL) / (256 * 8), 256, 0, stream>>>(
      in_w, inw_bf, 2 * DINNER * DMODEL);

  // 1. in-projection: xz = x @ in_w.T + in_b   (2048 x 4096, K=1024)
  gemm_bt_mfma<128><<<dim3(NTOK / 128, (2 * DINNER) / 128), 256, 0, stream>>>(
      x_bf, inw_bf, in_b, xz, 2 * DINNER, DMODEL);

  // 2. depthwise conv + SiLU gate -> xg (kills xz, x_bf, inw_bf)
  conv_gate_kernel<<<(NTOK * DINNER) / 256, 256, 0, stream>>>(
      xz, conv_w, conv_b, xg);

  // 2b. cast out_w (must follow conv: overlays dead xz region)
  cast_bf16_kernel<<<(DMODEL * DINNER) / (256 * 8), 256, 0, stream>>>(
      out_w, outw_bf, DMODEL * DINNER);

  // 3. x-projection -> proj
  xproj_kernel<<<NTOK, 64, 0, stream>>>(xg, xproj_w, proj);

  // 4. chunked selective scan -> yb_bf
  scan_phase1<<<dim3(DINNER / 256, CCH, 2), 256, 0, stream>>>(
      xg, proj, dt_w, dt_b, A_log, Sbuf, Hbuf);
  scan_phase2<<<(2 * DINNER * DSTATE) / 256, 256, 0, stream>>>(
      A_log, Sbuf, Hbuf);
  scan_phase3<<<dim3(DINNER / 256, CCH, 2), 256, 0, stream>>>(
      xg, proj, dt_w, dt_b, A_log, Dp, Hbuf, yb_bf);

  // 5. out-projection: out = y @ out_w.T   (2048 x 1024, K=2048)
  gemm_bt_mfma<64><<<dim3(NTOK / 128, DMODEL / 64), 256, 0, stream>>>(
      yb_bf, outw_bf, nullptr, out, DMODEL, DINNER);
}

// Round 5
// 239.229 us; speedup vs baseline: 3.9693x; 1.1039x over previous
//
#include <hip/hip_runtime.h>
#include <hip/hip_bf16.h>

// Problem shapes (fixed by setup_inputs):
//   b=2, L=1024, d_model=1024, d_inner=2048, d_state=16, D_CONV=4
#define NTOK   2048
#define DMODEL 1024
#define DINNER 2048
#define DSTATE 16
#define SEQLEN 1024
#define NPROJ  33   // 2*d_state + 1
#define CCH    32   // scan chunks per sequence
#define CT     32   // steps per chunk

typedef __attribute__((ext_vector_type(8))) short bf16x8;
typedef __attribute__((ext_vector_type(4))) float f32x4;
typedef __attribute__((ext_vector_type(8))) unsigned short us8;

__device__ __forceinline__ unsigned short f2bf(float f) {
  unsigned u = __float_as_uint(f);
  return (unsigned short)((u + 0x7FFFu + ((u >> 16) & 1u)) >> 16);  // RNE
}

__device__ __forceinline__ void gload_lds16(const void* g, void* l) {
  __builtin_amdgcn_global_load_lds(
      (const __attribute__((address_space(1))) unsigned int*)g,
      (__attribute__((address_space(3))) unsigned int*)l, 16, 0, 0);
}

// ---------------------------------------------------------------------------
// Fused fp32->bf16 cast of x (2M), in_w (4M), out_w (2M) into one contiguous
// bf16 region. Regions are 2M-element multiples so a thread's 8 elems never
// straddle a source boundary.
// ---------------------------------------------------------------------------
__global__ __launch_bounds__(256) void cast3_bf16_kernel(
    const float* __restrict__ s0, const float* __restrict__ s1,
    const float* __restrict__ s2, unsigned short* __restrict__ dst) {
  const int idx = (blockIdx.x * 256 + threadIdx.x) * 8;
  const float* src;
  int off;
  if (idx < (NTOK * DMODEL)) { src = s0; off = idx; }
  else if (idx < (NTOK * DMODEL + 2 * DINNER * DMODEL)) {
    src = s1; off = idx - NTOK * DMODEL;
  } else { src = s2; off = idx - (NTOK * DMODEL + 2 * DINNER * DMODEL); }
  const float4 a = *(const float4*)(src + off);
  const float4 b = *(const float4*)(src + off + 4);
  us8 o;
  o[0] = f2bf(a.x); o[1] = f2bf(a.y); o[2] = f2bf(a.z); o[3] = f2bf(a.w);
  o[4] = f2bf(b.x); o[5] = f2bf(b.y); o[6] = f2bf(b.z); o[7] = f2bf(b.w);
  *(us8*)(dst + idx) = o;
}

// ---------------------------------------------------------------------------
// bf16 MFMA GEMM: C[n,m] = sum_k A[n,k]*B[m,k] (+ bias[m]).
// Block tile 128 x BN; K-loop advances 64 per barrier pair as TWO 32-deep LDS
// stages (keeps the 64B-row layout: 2-way bank aliasing only, and satisfies
// global_load_lds' contiguous-dest rule). 4 waves in 2x2, wave tile 64 x BN/2.
// ---------------------------------------------------------------------------
template <int BN>
__global__ __launch_bounds__(256) void gemm_bt_mfma(
    const unsigned short* __restrict__ A, const unsigned short* __restrict__ B,
    const float* __restrict__ bias, float* __restrict__ C, int M, int K) {
  constexpr int TN = BN / 32;
  __shared__ unsigned short As[2][128 * 32];
  __shared__ unsigned short Bs[2][BN * 32];

  const int tid = threadIdx.x;
  const int wid = tid >> 6;
  const int lane = tid & 63;
  const int n0 = blockIdx.x * 128;
  const int m0 = blockIdx.y * BN;

  const int wave_m = wid & 1;
  const int wave_n = wid >> 1;
  const int lm = lane & 15;
  const int lq = lane >> 4;

  f32x4 acc[4][TN] = {};

  for (int k0 = 0; k0 < K; k0 += 64) {
    __syncthreads();
#pragma unroll
    for (int h = 0; h < 2; ++h) {
      const int kh = k0 + h * 32;
      // A: 512 chunks of 16B; chunk c -> row c>>2, k-offset (c&3)*8
#pragma unroll
      for (int j = 0; j < 2; ++j) {
        const int cb = j * 256 + wid * 64;
        const int c = cb + lane;
        gload_lds16(A + (size_t)(n0 + (c >> 2)) * K + kh + (c & 3) * 8,
                    &As[h][cb * 8]);
      }
#pragma unroll
      for (int j = 0; j < BN / 64; ++j) {
        const int cb = j * 256 + wid * 64;
        const int c = cb + lane;
        gload_lds16(B + (size_t)(m0 + (c >> 2)) * K + kh + (c & 3) * 8,
                    &Bs[h][cb * 8]);
      }
    }
    __syncthreads();

#pragma unroll
    for (int h = 0; h < 2; ++h) {
      bf16x8 af[4], bfr[TN];
#pragma unroll
      for (int tm = 0; tm < 4; ++tm)
        af[tm] = *(const bf16x8*)
            &As[h][(wave_m * 64 + tm * 16 + lm) * 32 + lq * 8];
#pragma unroll
      for (int tn = 0; tn < TN; ++tn)
        bfr[tn] = *(const bf16x8*)
            &Bs[h][(wave_n * (BN / 2) + tn * 16 + lm) * 32 + lq * 8];
#pragma unroll
      for (int tm = 0; tm < 4; ++tm)
#pragma unroll
        for (int tn = 0; tn < TN; ++tn)
          acc[tm][tn] = __builtin_amdgcn_mfma_f32_16x16x32_bf16(
              af[tm], bfr[tn], acc[tm][tn], 0, 0, 0);
    }
  }

  // C/D layout: reg r of lane holds D[row=(lane>>4)*4+r][col=lane&15]
#pragma unroll
  for (int tm = 0; tm < 4; ++tm) {
    const int row = n0 + wave_m * 64 + tm * 16 + lq * 4;
#pragma unroll
    for (int tn = 0; tn < TN; ++tn) {
      const int col = m0 + wave_n * (BN / 2) + tn * 16 + lm;
      const float bv = bias ? bias[col] : 0.f;
#pragma unroll
      for (int r = 0; r < 4; ++r)
        C[(size_t)(row + r) * M + col] = acc[tm][tn][r] + bv;
    }
  }
}

// ---------------------------------------------------------------------------
// Fused depthwise causal conv(4) + SiLU gate + x-projection.
// Block = 4 consecutive tokens (same sequence; 4 | SEQLEN), 256 threads,
// 8 channels/thread. Conv taps (7 rows) are loaded once per channel; xg stays
// in registers for the xproj partial sums (w re-read cut 4x vs per-token).
//   xg[n,i] written for scan phases; proj[n,r] = sum_i xg[n,i]*w[r,i].
// ---------------------------------------------------------------------------
__global__ __launch_bounds__(256) void conv_xproj_kernel(
    const float* __restrict__ xz, const float* __restrict__ cw,
    const float* __restrict__ cb, const float* __restrict__ w,
    float* __restrict__ xg, float* __restrict__ proj) {
  __shared__ float red[NPROJ][4][4];  // [r][token][wave]
  const int tid = threadIdx.x;
  const int wid = tid >> 6;
  const int lane = tid & 63;
  const int n0 = blockIdx.x * 4;
  const int l0 = n0 & (SEQLEN - 1);  // 0,4,8,... ; only l0==0 needs masking

  float xgv[4][8];
#pragma unroll
  for (int j = 0; j < 8; ++j) {
    const int i = tid + 256 * j;
    const float4 w4 = ((const float4*)cw)[i];
    const float cbv = cb[i];
    float taps[7];
#pragma unroll
    for (int d = 0; d < 7; ++d) {
      const bool valid = (l0 != 0) || (d >= 3);
      taps[d] = valid ? xz[(size_t)(n0 - 3 + d) * (2 * DINNER) + i] : 0.f;
    }
#pragma unroll
    for (int tok = 0; tok < 4; ++tok) {
      float acc = cbv;
      acc = fmaf(w4.x, taps[tok + 0], acc);
      acc = fmaf(w4.y, taps[tok + 1], acc);
      acc = fmaf(w4.z, taps[tok + 2], acc);
      acc = fmaf(w4.w, taps[tok + 3], acc);
      const float z = xz[(size_t)(n0 + tok) * (2 * DINNER) + DINNER + i];
      const float sig = 1.f / (1.f + __expf(-z));
      const float v = acc * (z * sig);
      xgv[tok][j] = v;
      xg[(size_t)(n0 + tok) * DINNER + i] = v;
    }
  }

  for (int r = 0; r < NPROJ; ++r) {
    float p0 = 0.f, p1 = 0.f, p2 = 0.f, p3 = 0.f;
#pragma unroll
    for (int j = 0; j < 8; ++j) {
      const float wv = w[(size_t)r * DINNER + tid + 256 * j];
      p0 = fmaf(xgv[0][j], wv, p0);
      p1 = fmaf(xgv[1][j], wv, p1);
      p2 = fmaf(xgv[2][j], wv, p2);
      p3 = fmaf(xgv[3][j], wv, p3);
    }
#pragma unroll
    for (int off = 32; off >= 1; off >>= 1) {
      p0 += __shfl_down(p0, off, 64);
      p1 += __shfl_down(p1, off, 64);
      p2 += __shfl_down(p2, off, 64);
      p3 += __shfl_down(p3, off, 64);
    }
    if (lane == 0) {
      red[r][0][wid] = p0; red[r][1][wid] = p1;
      red[r][2][wid] = p2; red[r][3][wid] = p3;
    }
  }
  __syncthreads();
  if (tid < NPROJ * 4) {
    const int r = tid >> 2;
    const int tok = tid & 3;
    const float s = red[r][tok][0] + red[r][tok][1] +
                    red[r][tok][2] + red[r][tok][3];
    proj[(size_t)(n0 + tok) * NPROJ + r] = s;
  }
}

// ---------------------------------------------------------------------------
// Chunked selective scan (delta = 1+exp(u) == exp(softplus(u)); chunk decay
// exp(Av*sum(delta)) since prod(exp) = exp(sum)).
// ---------------------------------------------------------------------------
__global__ __launch_bounds__(256) void scan_phase1(
    const float* __restrict__ xg, const float* __restrict__ proj,
    const float* __restrict__ dt_w, const float* __restrict__ dt_b,
    const float* __restrict__ A_log,
    float* __restrict__ Sbuf, float* __restrict__ Hbuf) {
  __shared__ float pl[CT][36];
  const int tid = threadIdx.x;
  const int i = blockIdx.x * 256 + tid;
  const int k = blockIdx.y;
  const int b = blockIdx.z;
  const int n0 = b * SEQLEN + k * CT;

  for (int e = tid; e < CT * NPROJ; e += 256) {
    const int t = e / NPROJ;
    const int c = e - t * NPROJ;
    pl[t][c] = proj[(size_t)(n0 + t) * NPROJ + c];
  }
  __syncthreads();

  const float dtw = dt_w[i], dtb = dt_b[i];
  float Av[DSTATE];
#pragma unroll
  for (int s = 0; s < DSTATE; ++s) Av[s] = -__expf(A_log[i * DSTATE + s]);

  float h[DSTATE] = {};
  float Ssum = 0.f;

  for (int t = 0; t < CT; ++t) {
    float fr[20];
#pragma unroll
    for (int j = 0; j < 5; ++j) {
      const float4 v = *(const float4*)&pl[t][j * 4];
      fr[4 * j + 0] = v.x; fr[4 * j + 1] = v.y;
      fr[4 * j + 2] = v.z; fr[4 * j + 3] = v.w;
    }
    const float delta = 1.f + __expf(fmaf(fr[0], dtw, dtb));
    Ssum += delta;
    const float x = xg[(size_t)(n0 + t) * DINNER + i];
    const float dx = delta * x;
#pragma unroll
    for (int s = 0; s < DSTATE; ++s)
      h[s] = fmaf(__expf(Av[s] * delta), h[s], fr[1 + s] * dx);
  }

  const size_t ck = (size_t)(b * CCH + k) * DINNER + i;
  Sbuf[ck] = Ssum;
  float4* Hq = (float4*)(Hbuf + ck * DSTATE);
#pragma unroll
  for (int q = 0; q < 4; ++q)
    Hq[q] = make_float4(h[4 * q], h[4 * q + 1], h[4 * q + 2], h[4 * q + 3]);
}

__global__ __launch_bounds__(256) void scan_phase2(
    const float* __restrict__ A_log, const float* __restrict__ Sbuf,
    float* __restrict__ Hbuf) {
  const int gid = blockIdx.x * 256 + threadIdx.x;
  const int s = gid & (DSTATE - 1);
  const int i = (gid >> 4) & (DINNER - 1);
  const int b = gid >> 15;
  const float Av = -__expf(A_log[i * DSTATE + s]);
  float H = 0.f;
  for (int k = 0; k < CCH; ++k) {
    const size_t ck = (size_t)(b * CCH + k) * DINNER + i;
    const float hk = Hbuf[ck * DSTATE + s];
    const float a = __expf(Av * Sbuf[ck]);
    Hbuf[ck * DSTATE + s] = H;
    H = fmaf(a, H, hk);
  }
}

__global__ __launch_bounds__(256) void scan_phase3(
    const float* __restrict__ xg, const float* __restrict__ proj,
    const float* __restrict__ dt_w, const float* __restrict__ dt_b,
    const float* __restrict__ A_log, const float* __restrict__ Dp,
    const float* __restrict__ Hbuf, unsigned short* __restrict__ y) {
  __shared__ float pl[CT][36];
  const int tid = threadIdx.x;
  const int i = blockIdx.x * 256 + tid;
  const int k = blockIdx.y;
  const int b = blockIdx.z;
  const int n0 = b * SEQLEN + k * CT;

  for (int e = tid; e < CT * NPROJ; e += 256) {
    const int t = e / NPROJ;
    const int c = e - t * NPROJ;
    pl[t][c] = proj[(size_t)(n0 + t) * NPROJ + c];
  }
  __syncthreads();

  const float dtw = dt_w[i], dtb = dt_b[i];
  const float Dv = Dp[i];
  float Av[DSTATE];
#pragma unroll
  for (int s = 0; s < DSTATE; ++s) Av[s] = -__expf(A_log[i * DSTATE + s]);

  const size_t ck = (size_t)(b * CCH + k) * DINNER + i;
  float h[DSTATE];
  const float4* Hq = (const float4*)(Hbuf + ck * DSTATE);
#pragma unroll
  for (int q = 0; q < 4; ++q) {
    const float4 v = Hq[q];
    h[4 * q + 0] = v.x; h[4 * q + 1] = v.y;
    h[4 * q + 2] = v.z; h[4 * q + 3] = v.w;
  }

  for (int t = 0; t < CT; ++t) {
    float fr[33];
#pragma unroll
    for (int j = 0; j < 8; ++j) {
      const float4 v = *(const float4*)&pl[t][j * 4];
      fr[4 * j + 0] = v.x; fr[4 * j + 1] = v.y;
      fr[4 * j + 2] = v.z; fr[4 * j + 3] = v.w;
    }
    fr[32] = pl[t][32];
    const float delta = 1.f + __expf(fmaf(fr[0], dtw, dtb));
    const float x = xg[(size_t)(n0 + t) * DINNER + i];
    const float dx = delta * x;
    float yt = 0.f;
#pragma unroll
    for (int s = 0; s < DSTATE; ++s) {
      h[s] = fmaf(__expf(Av[s] * delta), h[s], fr[1 + s] * dx);
      yt = fmaf(h[s], fr[17 + s], yt);
    }
    y[(size_t)(n0 + t) * DINNER + i] = f2bf(fmaf(Dv, x, yt));
  }
}

// ---------------------------------------------------------------------------
extern "C" void kernel_launch(void* const* d_in, const int* in_sizes, int n_in,
                              void* d_out, int out_size, void* d_ws, size_t ws_size,
                              hipStream_t stream) {
  const float* x       = (const float*)d_in[0];
  const float* in_w    = (const float*)d_in[1];
  const float* in_b    = (const float*)d_in[2];
  const float* conv_w  = (const float*)d_in[3];
  const float* conv_b  = (const float*)d_in[4];
  const float* xproj_w = (const float*)d_in[5];
  const float* dt_w    = (const float*)d_in[6];
  const float* dt_b    = (const float*)d_in[7];
  const float* A_log   = (const float*)d_in[8];
  const float* Dp      = (const float*)d_in[9];
  const float* out_w   = (const float*)d_in[10];
  float* out = (float*)d_out;

  // Workspace (float offsets) — fully DISJOINT (ws is 256 MiB; ~88 MB used):
  //   xz      @ 0         (8,388,608)   gemm1 -> conv_xproj
  //   xg      @ 8388608   (4,194,304)   conv_xproj -> p1/p3
  //   bf区    @ 12582912: x_bf (2M bf16) | inw_bf (4M bf16) | outw_bf (2M bf16)
  //           contiguous dest of cast3 (x, in_w, out_w in that order)
  //   yb_bf   @ 16777216  (4M bf16 = 2M floats)   p3 -> gemm2
  //   proj    @ 18874368  (67,584)
  //   Sbuf    @ 19398656  (131,072)
  //   Hbuf    @ 19922944  (2,097,152)
  float* ws = (float*)d_ws;
  float* xz   = ws;
  float* xg   = ws + 8388608;
  unsigned short* bf_base = (unsigned short*)(ws + 12582912);
  unsigned short* x_bf    = bf_base;
  unsigned short* inw_bf  = bf_base + (size_t)NTOK * DMODEL;
  unsigned short* outw_bf = bf_base + (size_t)NTOK * DMODEL + 2 * DINNER * DMODEL;
  unsigned short* yb_bf   = (unsigned short*)(ws + 16777216);
  float* proj = ws + 18874368;
  float* Sbuf = ws + 19398656;
  float* Hbuf = ws + 19922944;

  // 0. single fused cast: x (2M) + in_w (4M) + out_w (2M) -> bf16
  cast3_bf16_kernel<<<(8 * 1024 * 1024) / (256 * 8), 256, 0, stream>>>(
      x, in_w, out_w, bf_base);

  // 1. in-projection: xz = x @ in_w.T + in_b   (2048 x 4096, K=1024)
  gemm_bt_mfma<128><<<dim3(NTOK / 128, (2 * DINNER) / 128), 256, 0, stream>>>(
      x_bf, inw_bf, in_b, xz, 2 * DINNER, DMODEL);

  // 2. fused depthwise conv + SiLU gate + x-projection -> xg, proj
  conv_xproj_kernel<<<NTOK / 4, 256, 0, stream>>>(
      xz, conv_w, conv_b, xproj_w, xg, proj);

  // 3. chunked selective scan -> yb_bf
  scan_phase1<<<dim3(DINNER / 256, CCH, 2), 256, 0, stream>>>(
      xg, proj, dt_w, dt_b, A_log, Sbuf, Hbuf);
  scan_phase2<<<(2 * DINNER * DSTATE) / 256, 256, 0, stream>>>(
      A_log, Sbuf, Hbuf);
  scan_phase3<<<dim3(DINNER / 256, CCH, 2), 256, 0, stream>>>(
      xg, proj, dt_w, dt_b, A_log, Dp, Hbuf, yb_bf);

  // 4. out-projection: out = y @ out_w.T   (2048 x 1024, K=2048)
  gemm_bt_mfma<64><<<dim3(NTOK / 128, DMODEL / 64), 256, 0, stream>>>(
      yb_bf, outw_bf, nullptr, out, DMODEL, DINNER);
}

// Round 6
// 222.712 us; speedup vs baseline: 4.2636x; 1.0742x over previous
//
#include <hip/hip_runtime.h>
#include <hip/hip_bf16.h>

// Problem shapes (fixed by setup_inputs):
//   b=2, L=1024, d_model=1024, d_inner=2048, d_state=16, D_CONV=4
#define NTOK   2048
#define DMODEL 1024
#define DINNER 2048
#define DSTATE 16
#define SEQLEN 1024
#define NPROJ  33   // 2*d_state + 1
#define NPAD   48   // NPROJ padded for MFMA tiles
#define KSPLIT 16   // split-K factor for xproj GEMM
#define CCH    64   // scan chunks per sequence
#define CT     16   // steps per chunk

typedef __attribute__((ext_vector_type(8))) short bf16x8;
typedef __attribute__((ext_vector_type(4))) float f32x4;
typedef __attribute__((ext_vector_type(8))) unsigned short us8;

__device__ __forceinline__ unsigned short f2bf(float f) {
  unsigned u = __float_as_uint(f);
  return (unsigned short)((u + 0x7FFFu + ((u >> 16) & 1u)) >> 16);  // RNE
}

__device__ __forceinline__ void gload_lds16(const void* g, void* l) {
  __builtin_amdgcn_global_load_lds(
      (const __attribute__((address_space(1))) unsigned int*)g,
      (__attribute__((address_space(3))) unsigned int*)l, 16, 0, 0);
}

// ---------------------------------------------------------------------------
// Fused fp32->bf16 cast: x (2M) | in_w (4M) | out_w (2M) | xproj_w padded to
// 48x2048 (67584 real + zero pad). All region boundaries are multiples of 8.
// ---------------------------------------------------------------------------
#define CAST_N0 (NTOK * DMODEL)                       // 2097152
#define CAST_N1 (CAST_N0 + 2 * DINNER * DMODEL)       // 6291456
#define CAST_N2 (CAST_N1 + DMODEL * DINNER)           // 8388608
#define CAST_N3 (CAST_N2 + NPAD * DINNER)             // 8486912
__global__ __launch_bounds__(256) void cast4_bf16_kernel(
    const float* __restrict__ s0, const float* __restrict__ s1,
    const float* __restrict__ s2, const float* __restrict__ s3,
    unsigned short* __restrict__ dst) {
  const int idx = (blockIdx.x * 256 + threadIdx.x) * 8;
  const float* src;
  int off;
  if (idx < CAST_N0) { src = s0; off = idx; }
  else if (idx < CAST_N1) { src = s1; off = idx - CAST_N0; }
  else if (idx < CAST_N2) { src = s2; off = idx - CAST_N1; }
  else {
    off = idx - CAST_N2;
    if (off >= NPROJ * DINNER) {  // zero pad rows 33..47
      us8 z = {0, 0, 0, 0, 0, 0, 0, 0};
      *(us8*)(dst + idx) = z;
      return;
    }
    src = s3;
  }
  const float4 a = *(const float4*)(src + off);
  const float4 b = *(const float4*)(src + off + 4);
  us8 o;
  o[0] = f2bf(a.x); o[1] = f2bf(a.y); o[2] = f2bf(a.z); o[3] = f2bf(a.w);
  o[4] = f2bf(b.x); o[5] = f2bf(b.y); o[6] = f2bf(b.z); o[7] = f2bf(b.w);
  *(us8*)(dst + idx) = o;
}

// ---------------------------------------------------------------------------
// bf16 MFMA GEMM: C[n,m] = sum_k A[n,k]*B[m,k] (+ bias[m]).
// Block tile 128 x BN; K advances 64 per barrier pair (two 32-deep stages).
// ---------------------------------------------------------------------------
template <int BN>
__global__ __launch_bounds__(256) void gemm_bt_mfma(
    const unsigned short* __restrict__ A, const unsigned short* __restrict__ B,
    const float* __restrict__ bias, float* __restrict__ C, int M, int K) {
  constexpr int TN = BN / 32;
  __shared__ unsigned short As[2][128 * 32];
  __shared__ unsigned short Bs[2][BN * 32];

  const int tid = threadIdx.x;
  const int wid = tid >> 6;
  const int lane = tid & 63;
  const int n0 = blockIdx.x * 128;
  const int m0 = blockIdx.y * BN;

  const int wave_m = wid & 1;
  const int wave_n = wid >> 1;
  const int lm = lane & 15;
  const int lq = lane >> 4;

  f32x4 acc[4][TN] = {};

  for (int k0 = 0; k0 < K; k0 += 64) {
    __syncthreads();
#pragma unroll
    for (int h = 0; h < 2; ++h) {
      const int kh = k0 + h * 32;
#pragma unroll
      for (int j = 0; j < 2; ++j) {
        const int cb = j * 256 + wid * 64;
        const int c = cb + lane;
        gload_lds16(A + (size_t)(n0 + (c >> 2)) * K + kh + (c & 3) * 8,
                    &As[h][cb * 8]);
      }
#pragma unroll
      for (int j = 0; j < BN / 64; ++j) {
        const int cb = j * 256 + wid * 64;
        const int c = cb + lane;
        gload_lds16(B + (size_t)(m0 + (c >> 2)) * K + kh + (c & 3) * 8,
                    &Bs[h][cb * 8]);
      }
    }
    __syncthreads();

#pragma unroll
    for (int h = 0; h < 2; ++h) {
      bf16x8 af[4], bfr[TN];
#pragma unroll
      for (int tm = 0; tm < 4; ++tm)
        af[tm] = *(const bf16x8*)
            &As[h][(wave_m * 64 + tm * 16 + lm) * 32 + lq * 8];
#pragma unroll
      for (int tn = 0; tn < TN; ++tn)
        bfr[tn] = *(const bf16x8*)
            &Bs[h][(wave_n * (BN / 2) + tn * 16 + lm) * 32 + lq * 8];
#pragma unroll
      for (int tm = 0; tm < 4; ++tm)
#pragma unroll
        for (int tn = 0; tn < TN; ++tn)
          acc[tm][tn] = __builtin_amdgcn_mfma_f32_16x16x32_bf16(
              af[tm], bfr[tn], acc[tm][tn], 0, 0, 0);
    }
  }

#pragma unroll
  for (int tm = 0; tm < 4; ++tm) {
    const int row = n0 + wave_m * 64 + tm * 16 + lq * 4;
#pragma unroll
    for (int tn = 0; tn < TN; ++tn) {
      const int col = m0 + wave_n * (BN / 2) + tn * 16 + lm;
      const float bv = bias ? bias[col] : 0.f;
#pragma unroll
      for (int r = 0; r < 4; ++r)
        C[(size_t)(row + r) * M + col] = acc[tm][tn][r] + bv;
    }
  }
}

// ---------------------------------------------------------------------------
// Depthwise causal conv(4) + SiLU gate. Thread = (channel, 4 tokens):
// 7 taps loaded once, 4 outputs. Writes fp32 xg (scan) + bf16 xg (xproj mfma).
// Grid (NTOK/4, DINNER/256).
// ---------------------------------------------------------------------------
__global__ __launch_bounds__(256) void conv_gate_kernel(
    const float* __restrict__ xz, const float* __restrict__ cw,
    const float* __restrict__ cb, float* __restrict__ xg,
    unsigned short* __restrict__ xgb) {
  const int i = blockIdx.y * 256 + threadIdx.x;
  const int n0 = blockIdx.x * 4;
  const int l0 = n0 & (SEQLEN - 1);  // 0 only at sequence starts

  const float4 w4 = ((const float4*)cw)[i];
  const float cbv = cb[i];
  float taps[7];
#pragma unroll
  for (int d = 0; d < 7; ++d) {
    const bool valid = (l0 != 0) || (d >= 3);
    taps[d] = valid ? xz[(size_t)(n0 - 3 + d) * (2 * DINNER) + i] : 0.f;
  }
#pragma unroll
  for (int tok = 0; tok < 4; ++tok) {
    float acc = cbv;
    acc = fmaf(w4.x, taps[tok + 0], acc);
    acc = fmaf(w4.y, taps[tok + 1], acc);
    acc = fmaf(w4.z, taps[tok + 2], acc);
    acc = fmaf(w4.w, taps[tok + 3], acc);
    const float z = xz[(size_t)(n0 + tok) * (2 * DINNER) + DINNER + i];
    const float sig = 1.f / (1.f + __expf(-z));
    const float v = acc * (z * sig);
    const size_t o = (size_t)(n0 + tok) * DINNER + i;
    xg[o] = v;
    xgb[o] = f2bf(v);
  }
}

// ---------------------------------------------------------------------------
// xproj via MFMA, split-K: pp[kq][n][0..48) = xg[n, kq*128..+128) @ w^T.
// Grid (NTOK/128, KSPLIT). 4 waves, each 32 tokens x 48 feats (2x3 mfma tiles).
// ---------------------------------------------------------------------------
__global__ __launch_bounds__(256) void xproj_mfma_kernel(
    const unsigned short* __restrict__ xgb, const unsigned short* __restrict__ wp,
    float* __restrict__ pp) {
  __shared__ unsigned short As[128 * 32];
  __shared__ unsigned short Bs[NPAD * 32];

  const int tid = threadIdx.x;
  const int wid = tid >> 6;
  const int lane = tid & 63;
  const int n0 = blockIdx.x * 128;
  const int kbase = blockIdx.y * (DINNER / KSPLIT);  // 128 per split

  const int lm = lane & 15;
  const int lq = lane >> 4;

  f32x4 acc[2][3] = {};

  for (int it = 0; it < (DINNER / KSPLIT) / 32; ++it) {  // 4 iters
    const int k0 = kbase + it * 32;
    __syncthreads();
#pragma unroll
    for (int j = 0; j < 2; ++j) {
      const int cb = j * 256 + wid * 64;
      const int c = cb + lane;
      gload_lds16(xgb + (size_t)(n0 + (c >> 2)) * DINNER + k0 + (c & 3) * 8,
                  &As[cb * 8]);
    }
    if (wid < 3) {  // 192 chunks cover 48 rows x 64B
      const int cb = wid * 64;
      const int c = cb + lane;
      gload_lds16(wp + (size_t)(c >> 2) * DINNER + k0 + (c & 3) * 8,
                  &Bs[cb * 8]);
    }
    __syncthreads();

    bf16x8 af[2], bfr[3];
#pragma unroll
    for (int tm = 0; tm < 2; ++tm)
      af[tm] = *(const bf16x8*)&As[(wid * 32 + tm * 16 + lm) * 32 + lq * 8];
#pragma unroll
    for (int tn = 0; tn < 3; ++tn)
      bfr[tn] = *(const bf16x8*)&Bs[(tn * 16 + lm) * 32 + lq * 8];
#pragma unroll
    for (int tm = 0; tm < 2; ++tm)
#pragma unroll
      for (int tn = 0; tn < 3; ++tn)
        acc[tm][tn] = __builtin_amdgcn_mfma_f32_16x16x32_bf16(
            af[tm], bfr[tn], acc[tm][tn], 0, 0, 0);
  }

  float* base = pp + (size_t)blockIdx.y * NTOK * NPAD;
#pragma unroll
  for (int tm = 0; tm < 2; ++tm) {
    const int row = n0 + wid * 32 + tm * 16 + lq * 4;
#pragma unroll
    for (int tn = 0; tn < 3; ++tn) {
      const int col = tn * 16 + lm;
#pragma unroll
      for (int r = 0; r < 4; ++r)
        base[(size_t)(row + r) * NPAD + col] = acc[tm][tn][r];
    }
  }
}

// proj[n,r] = sum over KSPLIT partials
__global__ __launch_bounds__(256) void proj_reduce_kernel(
    const float* __restrict__ pp, float* __restrict__ proj) {
  const int gid = blockIdx.x * 256 + threadIdx.x;
  if (gid >= NTOK * NPROJ) return;
  const int n = gid / NPROJ;
  const int r = gid - n * NPROJ;
  float s = 0.f;
#pragma unroll
  for (int q = 0; q < KSPLIT; ++q)
    s += pp[((size_t)q * NTOK + n) * NPAD + r];
  proj[gid] = s;
}

// ---------------------------------------------------------------------------
// Chunked selective scan (delta = 1+exp(u) == exp(softplus(u)); chunk decay
// exp(Av*sum(delta)) since prod(exp) = exp(sum)).
// ---------------------------------------------------------------------------
__global__ __launch_bounds__(256) void scan_phase1(
    const float* __restrict__ xg, const float* __restrict__ proj,
    const float* __restrict__ dt_w, const float* __restrict__ dt_b,
    const float* __restrict__ A_log,
    float* __restrict__ Sbuf, float* __restrict__ Hbuf) {
  __shared__ float pl[CT][36];
  const int tid = threadIdx.x;
  const int i = blockIdx.x * 256 + tid;
  const int k = blockIdx.y;
  const int b = blockIdx.z;
  const int n0 = b * SEQLEN + k * CT;

  for (int e = tid; e < CT * NPROJ; e += 256) {
    const int t = e / NPROJ;
    const int c = e - t * NPROJ;
    pl[t][c] = proj[(size_t)(n0 + t) * NPROJ + c];
  }
  __syncthreads();

  const float dtw = dt_w[i], dtb = dt_b[i];
  float Av[DSTATE];
#pragma unroll
  for (int s = 0; s < DSTATE; ++s) Av[s] = -__expf(A_log[i * DSTATE + s]);

  float h[DSTATE] = {};
  float Ssum = 0.f;

  for (int t = 0; t < CT; ++t) {
    float fr[20];
#pragma unroll
    for (int j = 0; j < 5; ++j) {
      const float4 v = *(const float4*)&pl[t][j * 4];
      fr[4 * j + 0] = v.x; fr[4 * j + 1] = v.y;
      fr[4 * j + 2] = v.z; fr[4 * j + 3] = v.w;
    }
    const float delta = 1.f + __expf(fmaf(fr[0], dtw, dtb));
    Ssum += delta;
    const float x = xg[(size_t)(n0 + t) * DINNER + i];
    const float dx = delta * x;
#pragma unroll
    for (int s = 0; s < DSTATE; ++s)
      h[s] = fmaf(__expf(Av[s] * delta), h[s], fr[1 + s] * dx);
  }

  const size_t ck = (size_t)(b * CCH + k) * DINNER + i;
  Sbuf[ck] = Ssum;
  float4* Hq = (float4*)(Hbuf + ck * DSTATE);
#pragma unroll
  for (int q = 0; q < 4; ++q)
    Hq[q] = make_float4(h[4 * q], h[4 * q + 1], h[4 * q + 2], h[4 * q + 3]);
}

__global__ __launch_bounds__(256) void scan_phase2(
    const float* __restrict__ A_log, const float* __restrict__ Sbuf,
    float* __restrict__ Hbuf) {
  const int gid = blockIdx.x * 256 + threadIdx.x;
  const int s = gid & (DSTATE - 1);
  const int i = (gid >> 4) & (DINNER - 1);
  const int b = gid >> 15;
  const float Av = -__expf(A_log[i * DSTATE + s]);
  float H = 0.f;
  for (int k = 0; k < CCH; ++k) {
    const size_t ck = (size_t)(b * CCH + k) * DINNER + i;
    const float hk = Hbuf[ck * DSTATE + s];
    const float a = __expf(Av * Sbuf[ck]);
    Hbuf[ck * DSTATE + s] = H;
    H = fmaf(a, H, hk);
  }
}

__global__ __launch_bounds__(256) void scan_phase3(
    const float* __restrict__ xg, const float* __restrict__ proj,
    const float* __restrict__ dt_w, const float* __restrict__ dt_b,
    const float* __restrict__ A_log, const float* __restrict__ Dp,
    const float* __restrict__ Hbuf, unsigned short* __restrict__ y) {
  __shared__ float pl[CT][36];
  const int tid = threadIdx.x;
  const int i = blockIdx.x * 256 + tid;
  const int k = blockIdx.y;
  const int b = blockIdx.z;
  const int n0 = b * SEQLEN + k * CT;

  for (int e = tid; e < CT * NPROJ; e += 256) {
    const int t = e / NPROJ;
    const int c = e - t * NPROJ;
    pl[t][c] = proj[(size_t)(n0 + t) * NPROJ + c];
  }
  __syncthreads();

  const float dtw = dt_w[i], dtb = dt_b[i];
  const float Dv = Dp[i];
  float Av[DSTATE];
#pragma unroll
  for (int s = 0; s < DSTATE; ++s) Av[s] = -__expf(A_log[i * DSTATE + s]);

  const size_t ck = (size_t)(b * CCH + k) * DINNER + i;
  float h[DSTATE];
  const float4* Hq = (const float4*)(Hbuf + ck * DSTATE);
#pragma unroll
  for (int q = 0; q < 4; ++q) {
    const float4 v = Hq[q];
    h[4 * q + 0] = v.x; h[4 * q + 1] = v.y;
    h[4 * q + 2] = v.z; h[4 * q + 3] = v.w;
  }

  for (int t = 0; t < CT; ++t) {
    float fr[33];
#pragma unroll
    for (int j = 0; j < 8; ++j) {
      const float4 v = *(const float4*)&pl[t][j * 4];
      fr[4 * j + 0] = v.x; fr[4 * j + 1] = v.y;
      fr[4 * j + 2] = v.z; fr[4 * j + 3] = v.w;
    }
    fr[32] = pl[t][32];
    const float delta = 1.f + __expf(fmaf(fr[0], dtw, dtb));
    const float x = xg[(size_t)(n0 + t) * DINNER + i];
    const float dx = delta * x;
    float yt = 0.f;
#pragma unroll
    for (int s = 0; s < DSTATE; ++s) {
      h[s] = fmaf(__expf(Av[s] * delta), h[s], fr[1 + s] * dx);
      yt = fmaf(h[s], fr[17 + s], yt);
    }
    y[(size_t)(n0 + t) * DINNER + i] = f2bf(fmaf(Dv, x, yt));
  }
}

// ---------------------------------------------------------------------------
extern "C" void kernel_launch(void* const* d_in, const int* in_sizes, int n_in,
                              void* d_out, int out_size, void* d_ws, size_t ws_size,
                              hipStream_t stream) {
  const float* x       = (const float*)d_in[0];
  const float* in_w    = (const float*)d_in[1];
  const float* in_b    = (const float*)d_in[2];
  const float* conv_w  = (const float*)d_in[3];
  const float* conv_b  = (const float*)d_in[4];
  const float* xproj_w = (const float*)d_in[5];
  const float* dt_w    = (const float*)d_in[6];
  const float* dt_b    = (const float*)d_in[7];
  const float* A_log   = (const float*)d_in[8];
  const float* Dp      = (const float*)d_in[9];
  const float* out_w   = (const float*)d_in[10];
  float* out = (float*)d_out;

  // Workspace (float offsets), fully disjoint (~111 MB of the 256 MiB ws):
  //   xz    @ 0          8M    gemm1 -> conv
  //   xg    @ 8388608    4M    conv -> scan p1/p3 (fp32)
  //   xgb   @ 12582912   2M    conv -> xproj mfma (bf16 4M elems)
  //   casts @ 14680064   x_bf|inw_bf|outw_bf|wpad_bf (8486912 bf16)
  //   yb_bf @ 19398656   2M    p3 -> gemm2 (bf16 4M elems)
  //   pp    @ 20971520   1.5M  xproj partials (16 x 2048 x 48 fp32)
  //   proj  @ 22544384   67584
  //   Sbuf  @ 23068672   262144
  //   Hbuf  @ 23592960   4M
  float* ws = (float*)d_ws;
  float* xz = ws;
  float* xg = ws + 8388608;
  unsigned short* xgb = (unsigned short*)(ws + 12582912);
  unsigned short* bf_base = (unsigned short*)(ws + 14680064);
  unsigned short* x_bf    = bf_base;
  unsigned short* inw_bf  = bf_base + CAST_N0;
  unsigned short* outw_bf = bf_base + CAST_N1;
  unsigned short* wpad_bf = bf_base + CAST_N2;
  unsigned short* yb_bf = (unsigned short*)(ws + 19398656);
  float* pp   = ws + 20971520;
  float* proj = ws + 22544384;
  float* Sbuf = ws + 23068672;
  float* Hbuf = ws + 23592960;

  // 0. fused cast: x, in_w, out_w, xproj_w(padded) -> bf16
  cast4_bf16_kernel<<<CAST_N3 / (256 * 8), 256, 0, stream>>>(
      x, in_w, out_w, xproj_w, bf_base);

  // 1. in-projection: xz = x @ in_w.T + in_b   (2048 x 4096, K=1024)
  gemm_bt_mfma<128><<<dim3(NTOK / 128, (2 * DINNER) / 128), 256, 0, stream>>>(
      x_bf, inw_bf, in_b, xz, 2 * DINNER, DMODEL);

  // 2. depthwise conv + SiLU gate -> xg (fp32) + xgb (bf16)
  conv_gate_kernel<<<dim3(NTOK / 4, DINNER / 256), 256, 0, stream>>>(
      xz, conv_w, conv_b, xg, xgb);

  // 3. x-projection: MFMA split-K partials, then reduce
  xproj_mfma_kernel<<<dim3(NTOK / 128, KSPLIT), 256, 0, stream>>>(
      xgb, wpad_bf, pp);
  proj_reduce_kernel<<<(NTOK * NPROJ + 255) / 256, 256, 0, stream>>>(pp, proj);

  // 4. chunked selective scan -> yb_bf
  scan_phase1<<<dim3(DINNER / 256, CCH, 2), 256, 0, stream>>>(
      xg, proj, dt_w, dt_b, A_log, Sbuf, Hbuf);
  scan_phase2<<<(2 * DINNER * DSTATE) / 256, 256, 0, stream>>>(
      A_log, Sbuf, Hbuf);
  scan_phase3<<<dim3(DINNER / 256, CCH, 2), 256, 0, stream>>>(
      xg, proj, dt_w, dt_b, A_log, Dp, Hbuf, yb_bf);

  // 5. out-projection: out = y @ out_w.T   (2048 x 1024, K=2048)
  gemm_bt_mfma<64><<<dim3(NTOK / 128, DMODEL / 64), 256, 0, stream>>>(
      yb_bf, outw_bf, nullptr, out, DMODEL, DINNER);
}